// Round 6
// baseline (176.290 us; speedup 1.0000x reference)
//
#include <hip/hip_runtime.h>

#define D 64
#define DD 4096
#define DDD 262144
#define K 27

typedef _Float16 half8  __attribute__((ext_vector_type(8)));
typedef _Float16 half2v __attribute__((ext_vector_type(2)));
typedef float    f32x4  __attribute__((ext_vector_type(4)));
typedef float    f32x2  __attribute__((ext_vector_type(2)));
typedef float    f32x16 __attribute__((ext_vector_type(16)));

// tile 8x4x2 voxels (x,y,z); halo = tile + 2 each side
#define HX 12
#define HY 8
#define HZ 6
#define HROW 12
#define HPLN 96
#define HSP  576
#define CPAD 24          // f16/slot: 48B = b128-aligned + 8-phase bank cycling
#define VSLOT 24         // val-slab f16 per voxel (48B, same trick)

#define WSW_CH (14*6*64)       // Wsw: 5376 chunks x 8 f16 = 86016 B
#define KSW_CH (27*64)         // Ksw: 1728 chunks x 8 f16 = 27648 B
#define KSW_OFF 88064          // byte offset of Ksw in d_ws

__device__ inline half2v h2of(half8 v, int d) {
    half2v r; r.x = v[2*d]; r.y = v[2*d+1]; return r;
}

// ---------------- prep: pk -> Wsw (phase-1 A-frags), kern -> Ksw (phase-2 A-frags) ----
// Wsw chunk t=(s*6+mt)*64+lane: m=16mt+(lane&15); k=32s+8*(lane>>4)+j; W[m][k]=pk[kt][c][m], k=kt*16+c
// Ksw chunk u=kt*64+lane (32x32x16 A): m=lane&31 (o if <16 else 0-row), k=(lane>>5)*8+j=c
__global__ __launch_bounds__(256) void prep_weights(const float* __restrict__ pk,
                                                    const float* __restrict__ kern,
                                                    _Float16* __restrict__ Wsw,
                                                    _Float16* __restrict__ Ksw) {
    int t = blockIdx.x * 256 + threadIdx.x;
    if (t < WSW_CH) {
        int lane = t & 63;
        int sm = t >> 6;
        int s = sm / 6, mt = sm - 6 * s;
        int m = mt * 16 + (lane & 15);
        int q = lane >> 4;
        half8 w;
#pragma unroll
        for (int j = 0; j < 8; ++j) {
            int k = 32 * s + 8 * q + j;
            int kt = k >> 4, c = k & 15;
            float wv = (kt < K && m < 81) ? pk[kt * 1296 + c * 81 + m] : 0.0f;
            w[j] = (_Float16)wv;
        }
        *(half8*)(Wsw + t * 8) = w;
    } else if (t < WSW_CH + KSW_CH) {
        int u = t - WSW_CH;
        int kt = u >> 6, lane = u & 63;
        int m = lane & 31, kh = lane >> 5;
        half8 w;
#pragma unroll
        for (int j = 0; j < 8; ++j) {
            int c = kh * 8 + j;
            float wv = (m < 16) ? kern[kt * 256 + c * 16 + m] : 0.0f;
            w[j] = (_Float16)wv;
        }
        *(half8*)(Ksw + u * 8) = w;
    }
}

// ---------------- main fused kernel ----------------
__global__ __launch_bounds__(256, 3) void deform_main(
    const float* __restrict__ x,          // [16][64][64][64] fp32
    const _Float16* __restrict__ Wsw,     // phase-1 A-frags
    const _Float16* __restrict__ Ksw,     // phase-2 A-frags
    float* __restrict__ out)              // [16][64][64][64]
{
    __shared__ _Float16 s_h[HSP * CPAD];    // 27648 B halo; reused for reduction
    __shared__ _Float16 s_off[81 * 64];     // 10368 B offsets f16
    __shared__ _Float16 s_v[4 * 64 * VSLOT];// 12288 B per-wave val slabs

    const int tid  = threadIdx.x;
    const int lane = tid & 63;
    const int wave = __builtin_amdgcn_readfirstlane(tid >> 6);

    const int bx0 = blockIdx.x * 8;
    const int by0 = blockIdx.y * 4;
    const int bz0 = blockIdx.z * 2;

    // ---- Phase 0: stage halo, fp32 -> channel-last f16 inline ----
    for (int i = tid; i < HSP; i += 256) {
        int z = i / HPLN;
        int r = i - z * HPLN;
        int y = r / HROW;
        int xx = r - y * HROW;
        int gz = bz0 - 2 + z, gy = by0 - 2 + y, gx = bx0 - 2 + xx;
        bool in = (unsigned)gz < D && (unsigned)gy < D && (unsigned)gx < D;
        half8 a = {}, b = {};
        if (in) {
            const float* p = x + (gz * DD + gy * D + gx);
#pragma unroll
            for (int c = 0; c < 8; ++c) a[c] = (_Float16)p[c * DDD];
#pragma unroll
            for (int c = 0; c < 8; ++c) b[c] = (_Float16)p[(c + 8) * DDD];
        }
        *(half8*)(s_h + i * CPAD)     = a;
        *(half8*)(s_h + i * CPAD + 8) = b;
    }
    __syncthreads();

    // ---- Phase 1: offset conv as f16 MFMA implicit GEMM (M=96,K=448,N=64) ----
    {
        const int n = lane & 15, q = lane >> 4;
        const int vtz = wave >> 1;
        const int vty = 2 * (wave & 1) + (n >> 3);
        const int vtx = n & 7;
        f32x4 acc[6] = {};
        for (int s = 0; s < 14; ++s) {
            int kt = 2 * s + (q >> 1);
            int ktc = (kt < K) ? kt : 0;              // pad taps: W rows are zero
            int kd = ktc / 9, kh = (ktc / 3) % 3, kw = ktc % 3;
            int idx = (vtz + kd + 1) * HPLN + (vty + kh + 1) * HROW + (vtx + kw + 1);
            half8 bfrag = *(const half8*)(s_h + idx * CPAD + (q & 1) * 8);
#pragma unroll
            for (int mt = 0; mt < 6; ++mt) {
                half8 afrag = *(const half8*)(Wsw + ((s * 6 + mt) * 64 + lane) * 8);
                acc[mt] = __builtin_amdgcn_mfma_f32_16x16x32_f16(afrag, bfrag, acc[mt], 0, 0, 0);
            }
        }
        const int v = wave * 16 + n;
#pragma unroll
        for (int mt = 0; mt < 6; ++mt)
#pragma unroll
            for (int r = 0; r < 4; ++r) {
                int o = mt * 16 + q * 4 + r;
                if (o < 81) s_off[o * 64 + v] = (_Float16)acc[mt][r];
            }
    }
    __syncthreads();

    // ---- Phase 2: packed-f16 trilinear interp + MFMA tap/channel contraction ----
    const int tx = lane & 7, ty = (lane >> 3) & 3, tz = lane >> 5;
    const int gz = bz0 + tz, gy = by0 + ty, gx = bx0 + tx;
    const int l31 = lane & 31, lh = lane >> 5;
    _Float16* sv = s_v + wave * 64 * VSLOT;

    f32x16 acc2[2] = {};                  // C[o(+zero rows)][64 voxels]

    const int ntaps = (wave < 3) ? 7 : 6;
    for (int t = 0; t < ntaps; ++t) {
        const int kt = wave * 7 + t;
        const int kd = kt / 9, kh = (kt / 3) % 3, kw = kt % 3;
        float cz = (float)(gz + kd - 1) + (float)s_off[(3 * kt + 0) * 64 + lane];
        float cy = (float)(gy + kh - 1) + (float)s_off[(3 * kt + 1) * 64 + lane];
        float cx = (float)(gx + kw - 1) + (float)s_off[(3 * kt + 2) * 64 + lane];
        float zf = floorf(cz), yf = floorf(cy), xf = floorf(cx);
        float fz = cz - zf, fy = cy - yf, fx = cx - xf;
        int z0 = (int)zf, y0 = (int)yf, x0 = (int)xf;
        int hz0 = z0 - bz0 + 2, hy0 = y0 - by0 + 2, hx0 = x0 - bx0 + 2;

        half2v val2[8] = {};
        if ((unsigned)hz0 < (unsigned)(HZ - 1) && (unsigned)hy0 < (unsigned)(HY - 1)
            && (unsigned)hx0 < (unsigned)(HX - 1)) {
#pragma unroll
            for (int dz = 0; dz < 2; ++dz) {
                float wz = dz ? fz : 1.0f - fz;
#pragma unroll
                for (int dy = 0; dy < 2; ++dy) {
                    float wzy = wz * (dy ? fy : 1.0f - fy);
#pragma unroll
                    for (int dx = 0; dx < 2; ++dx) {
                        float w = wzy * (dx ? fx : 1.0f - fx);
                        int idx = (hz0 + dz) * HPLN + (hy0 + dy) * HROW + (hx0 + dx);
                        half8 c0 = *(const half8*)(s_h + idx * CPAD);
                        half8 c1 = *(const half8*)(s_h + idx * CPAD + 8);
                        _Float16 wh = (_Float16)w;
                        half2v w2; w2.x = wh; w2.y = wh;
#pragma unroll
                        for (int d = 0; d < 4; ++d)
                            val2[d] += w2 * h2of(c0, d);
#pragma unroll
                        for (int d = 0; d < 4; ++d)
                            val2[d + 4] += w2 * h2of(c1, d);
                    }
                }
            }
        } else {
            // rare: |offset| >= 1 pushed a corner outside the halo
            f32x2 valf[8] = {};
#pragma unroll
            for (int dz = 0; dz < 2; ++dz) {
                int zi = z0 + dz;
                float wz = dz ? fz : 1.0f - fz;
#pragma unroll
                for (int dy = 0; dy < 2; ++dy) {
                    int yi = y0 + dy;
                    float wzy = wz * (dy ? fy : 1.0f - fy);
#pragma unroll
                    for (int dx = 0; dx < 2; ++dx) {
                        int xi = x0 + dx;
                        if ((unsigned)zi < D && (unsigned)yi < D && (unsigned)xi < D) {
                            float w = wzy * (dx ? fx : 1.0f - fx);
                            int base = zi * DD + yi * D + xi;
#pragma unroll
                            for (int c = 0; c < 16; ++c)
                                valf[c >> 1][c & 1] += w * x[c * DDD + base];
                        }
                    }
                }
            }
#pragma unroll
            for (int d = 0; d < 8; ++d) {
                val2[d].x = (_Float16)valf[d].x;
                val2[d].y = (_Float16)valf[d].y;
            }
        }

        // stash this lane's 16-ch val in the wave slab (lane = voxel)
        half8 v0, v1;
#pragma unroll
        for (int d = 0; d < 4; ++d) { v0[2*d] = val2[d].x;     v0[2*d+1] = val2[d].y; }
#pragma unroll
        for (int d = 0; d < 4; ++d) { v1[2*d] = val2[d+4].x;   v1[2*d+1] = val2[d+4].y; }
        *(half8*)(sv + lane * VSLOT)     = v0;
        *(half8*)(sv + lane * VSLOT + 8) = v1;
        asm volatile("s_waitcnt lgkmcnt(0)" ::: "memory");  // cross-lane LDS handoff

        // A = kern tap slice (rows 16..31 zero), B = [c][voxel] from slab
        half8 af = *(const half8*)(Ksw + (kt * 64 + lane) * 8);
        half8 b0 = *(const half8*)(sv + l31 * VSLOT + lh * 8);
        acc2[0] = __builtin_amdgcn_mfma_f32_32x32x16_f16(af, b0, acc2[0], 0, 0, 0);
        half8 b1 = *(const half8*)(sv + (32 + l31) * VSLOT + lh * 8);
        acc2[1] = __builtin_amdgcn_mfma_f32_32x32x16_f16(af, b1, acc2[1], 0, 0, 0);
        asm volatile("" ::: "memory");   // keep next tap's stores after these reads
    }

    // ---- cross-wave reduction (reuse halo LDS) ----
    __syncthreads();
    float* s_red = (float*)s_h;          // [4][64][17] f32 = 17408 B
#pragma unroll
    for (int g = 0; g < 2; ++g)
#pragma unroll
        for (int r = 0; r < 8; ++r) {
            int o = (r & 3) + 8 * (r >> 2) + 4 * lh;     // 0..15
            s_red[(wave * 64 + g * 32 + l31) * 17 + o] = acc2[g][r];
        }
    __syncthreads();

#pragma unroll
    for (int j = 0; j < 4; ++j) {
        int o = wave * 4 + j;
        float s = s_red[(0 * 64 + lane) * 17 + o]
                + s_red[(1 * 64 + lane) * 17 + o]
                + s_red[(2 * 64 + lane) * 17 + o]
                + s_red[(3 * 64 + lane) * 17 + o];
        out[o * DDD + gz * DD + gy * D + gx] = s;
    }
}

extern "C" void kernel_launch(void* const* d_in, const int* in_sizes, int n_in,
                              void* d_out, int out_size, void* d_ws, size_t ws_size,
                              hipStream_t stream) {
    const float* x    = (const float*)d_in[0];
    const float* kern = (const float*)d_in[1];
    const float* pk   = (const float*)d_in[2];
    float* out = (float*)d_out;

    _Float16* Wsw = (_Float16*)d_ws;
    _Float16* Ksw = (_Float16*)((char*)d_ws + KSW_OFF);

    prep_weights<<<28, 256, 0, stream>>>(pk, kern, Wsw, Ksw);
    deform_main<<<dim3(8, 16, 32), 256, 0, stream>>>(x, Wsw, Ksw, out);
}

// Round 7
// 163.848 us; speedup vs baseline: 1.0759x; 1.0759x over previous
//
#include <hip/hip_runtime.h>

#define D 64
#define DD 4096
#define DDD 262144
#define K 27

typedef _Float16 half8  __attribute__((ext_vector_type(8)));
typedef _Float16 half2v __attribute__((ext_vector_type(2)));
typedef float    f32x4  __attribute__((ext_vector_type(4)));
typedef float    f32x2  __attribute__((ext_vector_type(2)));
typedef float    f32x16 __attribute__((ext_vector_type(16)));

// tile 8x4x2 voxels (x,y,z); halo = tile + 2 each side
#define HX 12
#define HY 8
#define HZ 6
#define HROW 12
#define HPLN 96
#define HSP  576
#define CPAD 24          // f16/slot: 48B = b128-aligned + 8-phase bank cycling

#define WSW_CH (14*6*64)       // Wsw: 5376 chunks x 8 f16 = 86016 B
#define KSW_CH (27*64)         // Ksw: 1728 chunks x 8 f16 = 27648 B
#define KSW_OFF 88064          // byte offset of Ksw in d_ws

__device__ inline half2v h2of(half8 v, int d) {
    half2v r; r.x = v[2*d]; r.y = v[2*d+1]; return r;
}

// ---------------- prep: pk -> Wsw (phase-1 A-frags), kern -> Ksw (phase-2 A-frags) ----
// Wsw chunk t=(s*6+mt)*64+lane: m=16mt+(lane&15); k=32s+8*(lane>>4)+j; W[m][k]=pk[kt][c][m], k=kt*16+c
// Ksw chunk u=kt*64+lane (32x32x16 A): m=lane&31 (o if <16 else 0-row), k=(lane>>5)*8+j=c
__global__ __launch_bounds__(256) void prep_weights(const float* __restrict__ pk,
                                                    const float* __restrict__ kern,
                                                    _Float16* __restrict__ Wsw,
                                                    _Float16* __restrict__ Ksw) {
    int t = blockIdx.x * 256 + threadIdx.x;
    if (t < WSW_CH) {
        int lane = t & 63;
        int sm = t >> 6;
        int s = sm / 6, mt = sm - 6 * s;
        int m = mt * 16 + (lane & 15);
        int q = lane >> 4;
        half8 w;
#pragma unroll
        for (int j = 0; j < 8; ++j) {
            int k = 32 * s + 8 * q + j;
            int kt = k >> 4, c = k & 15;
            float wv = (kt < K && m < 81) ? pk[kt * 1296 + c * 81 + m] : 0.0f;
            w[j] = (_Float16)wv;
        }
        *(half8*)(Wsw + t * 8) = w;
    } else if (t < WSW_CH + KSW_CH) {
        int u = t - WSW_CH;
        int kt = u >> 6, lane = u & 63;
        int m = lane & 31, kh = lane >> 5;
        half8 w;
#pragma unroll
        for (int j = 0; j < 8; ++j) {
            int c = kh * 8 + j;
            float wv = (m < 16) ? kern[kt * 256 + c * 16 + m] : 0.0f;
            w[j] = (_Float16)wv;
        }
        *(half8*)(Ksw + u * 8) = w;
    }
}

// ---------------- main fused kernel ----------------
__global__ __launch_bounds__(256, 4) void deform_main(
    const float* __restrict__ x,          // [16][64][64][64] fp32
    const _Float16* __restrict__ Wsw,     // phase-1 A-frags
    const _Float16* __restrict__ Ksw,     // phase-2 A-frags
    float* __restrict__ out)              // [16][64][64][64]
{
    __shared__ _Float16 s_h[HSP * CPAD];    // 27648 B halo; reused for reduction
    __shared__ _Float16 s_off[81 * 64];     // 10368 B offsets f16
    // total 38016 B -> 4 blocks/CU

    const int tid  = threadIdx.x;
    const int lane = tid & 63;
    const int wave = __builtin_amdgcn_readfirstlane(tid >> 6);

    const int bx0 = blockIdx.x * 8;
    const int by0 = blockIdx.y * 4;
    const int bz0 = blockIdx.z * 2;

    // ---- Phase 0: stage halo, fp32 -> channel-last f16 inline ----
    for (int i = tid; i < HSP; i += 256) {
        int z = i / HPLN;
        int r = i - z * HPLN;
        int y = r / HROW;
        int xx = r - y * HROW;
        int gz = bz0 - 2 + z, gy = by0 - 2 + y, gx = bx0 - 2 + xx;
        bool in = (unsigned)gz < D && (unsigned)gy < D && (unsigned)gx < D;
        half8 a = {}, b = {};
        if (in) {
            const float* p = x + (gz * DD + gy * D + gx);
#pragma unroll
            for (int c = 0; c < 8; ++c) a[c] = (_Float16)p[c * DDD];
#pragma unroll
            for (int c = 0; c < 8; ++c) b[c] = (_Float16)p[(c + 8) * DDD];
        }
        *(half8*)(s_h + i * CPAD)     = a;
        *(half8*)(s_h + i * CPAD + 8) = b;
    }
    __syncthreads();

    // ---- Phase 1: offset conv as f16 MFMA implicit GEMM (M=96,K=448,N=64) ----
    {
        const int n = lane & 15, q = lane >> 4;
        const int vtz = wave >> 1;
        const int vty = 2 * (wave & 1) + (n >> 3);
        const int vtx = n & 7;
        f32x4 acc[6] = {};
        for (int s = 0; s < 14; ++s) {
            int kt = 2 * s + (q >> 1);
            int ktc = (kt < K) ? kt : 0;              // pad taps: W rows are zero
            int kd = ktc / 9, kh = (ktc / 3) % 3, kw = ktc % 3;
            int idx = (vtz + kd + 1) * HPLN + (vty + kh + 1) * HROW + (vtx + kw + 1);
            half8 bfrag = *(const half8*)(s_h + idx * CPAD + (q & 1) * 8);
#pragma unroll
            for (int mt = 0; mt < 6; ++mt) {
                half8 afrag = *(const half8*)(Wsw + ((s * 6 + mt) * 64 + lane) * 8);
                acc[mt] = __builtin_amdgcn_mfma_f32_16x16x32_f16(afrag, bfrag, acc[mt], 0, 0, 0);
            }
        }
        const int v = wave * 16 + n;
#pragma unroll
        for (int mt = 0; mt < 6; ++mt)
#pragma unroll
            for (int r = 0; r < 4; ++r) {
                int o = mt * 16 + q * 4 + r;
                if (o < 81) s_off[o * 64 + v] = (_Float16)acc[mt][r];
            }
    }
    __syncthreads();

    // ---- Phase 2: each lane gathers its own MFMA B-fragment ----
    // wave parity -> z-half (h): waves 0,2 cover voxels 0..31, waves 1,3 cover 32..63.
    // wave>>1 -> tap parity: w0/w1 even taps (14), w2/w3 odd taps (13).
    // lane l: voxel v = h*32 + (l&31), channels (l>>5)*8 .. +8  == B-frag layout.
    const int l31 = lane & 31, lh = lane >> 5;
    const int h = wave & 1;
    const int kpar = wave >> 1;
    const int v = h * 32 + l31;
    const int tx = v & 7, ty = (v >> 3) & 3, tz = h;
    const int gz = bz0 + tz, gy = by0 + ty, gx = bx0 + tx;

    f32x16 acc2 = {};                     // C[o(+zero rows)][32 voxels of half h]

    for (int k2 = 0; k2 < 14; ++k2) {
        const int kt = 2 * k2 + kpar;
        if (kt >= K) break;               // wave-uniform (only odd-parity waves)
        const int kd = kt / 9, kh = (kt / 3) % 3, kw = kt % 3;
        float cz = (float)(gz + kd - 1) + (float)s_off[(3 * kt + 0) * 64 + v];
        float cy = (float)(gy + kh - 1) + (float)s_off[(3 * kt + 1) * 64 + v];
        float cx = (float)(gx + kw - 1) + (float)s_off[(3 * kt + 2) * 64 + v];
        float zf = floorf(cz), yf = floorf(cy), xf = floorf(cx);
        float fz = cz - zf, fy = cy - yf, fx = cx - xf;
        int z0 = (int)zf, y0 = (int)yf, x0 = (int)xf;
        int hz0 = z0 - bz0 + 2, hy0 = y0 - by0 + 2, hx0 = x0 - bx0 + 2;

        half2v val2[4] = {};              // this lane's 8 channels (4 x half2)
        if ((unsigned)hz0 < (unsigned)(HZ - 1) && (unsigned)hy0 < (unsigned)(HY - 1)
            && (unsigned)hx0 < (unsigned)(HX - 1)) {
#pragma unroll
            for (int dz = 0; dz < 2; ++dz) {
                float wz = dz ? fz : 1.0f - fz;
#pragma unroll
                for (int dy = 0; dy < 2; ++dy) {
                    float wzy = wz * (dy ? fy : 1.0f - fy);
#pragma unroll
                    for (int dx = 0; dx < 2; ++dx) {
                        float w = wzy * (dx ? fx : 1.0f - fx);
                        int idx = (hz0 + dz) * HPLN + (hy0 + dy) * HROW + (hx0 + dx);
                        half8 cc = *(const half8*)(s_h + idx * CPAD + lh * 8);
                        _Float16 wh = (_Float16)w;
                        half2v w2; w2.x = wh; w2.y = wh;
#pragma unroll
                        for (int d = 0; d < 4; ++d)
                            val2[d] += w2 * h2of(cc, d);
                    }
                }
            }
        } else {
            // rare: |offset| >= 1 pushed a corner outside the halo
            f32x2 valf[4] = {};
#pragma unroll
            for (int dz = 0; dz < 2; ++dz) {
                int zi = z0 + dz;
                float wz = dz ? fz : 1.0f - fz;
#pragma unroll
                for (int dy = 0; dy < 2; ++dy) {
                    int yi = y0 + dy;
                    float wzy = wz * (dy ? fy : 1.0f - fy);
#pragma unroll
                    for (int dx = 0; dx < 2; ++dx) {
                        int xi = x0 + dx;
                        if ((unsigned)zi < D && (unsigned)yi < D && (unsigned)xi < D) {
                            float w = wzy * (dx ? fx : 1.0f - fx);
                            int base = zi * DD + yi * D + xi;
#pragma unroll
                            for (int d = 0; d < 4; ++d) {
                                valf[d].x += w * x[(lh * 8 + 2 * d)     * DDD + base];
                                valf[d].y += w * x[(lh * 8 + 2 * d + 1) * DDD + base];
                            }
                        }
                    }
                }
            }
#pragma unroll
            for (int d = 0; d < 4; ++d) {
                val2[d].x = (_Float16)valf[d].x;
                val2[d].y = (_Float16)valf[d].y;
            }
        }

        // registers already ARE the B-fragment: B[k=ch][n=voxel]
        half8 bf;
#pragma unroll
        for (int d = 0; d < 4; ++d) { bf[2*d] = val2[d].x; bf[2*d+1] = val2[d].y; }
        half8 af = *(const half8*)(Ksw + (kt * 64 + lane) * 8);
        acc2 = __builtin_amdgcn_mfma_f32_32x32x16_f16(af, bf, acc2, 0, 0, 0);
    }

    // ---- cross-wave reduction (reuse halo LDS) ----
    // wave w wrote voxels (w&1)*32+l31; halves are summed over waves {h, h+2}.
    __syncthreads();
    float* s_red = (float*)s_h;           // 128 rows x 17 f32 = 8704 B
#pragma unroll
    for (int r = 0; r < 8; ++r) {
        int o = (r & 3) + 8 * (r >> 2) + 4 * lh;     // 0..15 (rows >=16 are zero pad)
        s_red[(wave * 32 + l31) * 17 + o] = acc2[r];
    }
    __syncthreads();

#pragma unroll
    for (int j = 0; j < 4; ++j) {
        int o = wave * 4 + j;
        float s = s_red[lane * 17 + o] + s_red[(64 + lane) * 17 + o];
        out[o * DDD + (bz0 + (lane >> 5)) * DD + (by0 + ((lane >> 3) & 3)) * D
            + (bx0 + (lane & 7))] = s;
    }
}

extern "C" void kernel_launch(void* const* d_in, const int* in_sizes, int n_in,
                              void* d_out, int out_size, void* d_ws, size_t ws_size,
                              hipStream_t stream) {
    const float* x    = (const float*)d_in[0];
    const float* kern = (const float*)d_in[1];
    const float* pk   = (const float*)d_in[2];
    float* out = (float*)d_out;

    _Float16* Wsw = (_Float16*)d_ws;
    _Float16* Ksw = (_Float16*)((char*)d_ws + KSW_OFF);

    prep_weights<<<28, 256, 0, stream>>>(pk, kern, Wsw, Ksw);
    deform_main<<<dim3(8, 16, 32), 256, 0, stream>>>(x, Wsw, Ksw, out);
}

// Round 8
// 155.519 us; speedup vs baseline: 1.1336x; 1.0536x over previous
//
#include <hip/hip_runtime.h>

#define D 64
#define DD 4096
#define DDD 262144
#define K 27

typedef _Float16 half8  __attribute__((ext_vector_type(8)));
typedef _Float16 half2v __attribute__((ext_vector_type(2)));
typedef float    f32x4  __attribute__((ext_vector_type(4)));
typedef float    f32x2  __attribute__((ext_vector_type(2)));

// tile 8x4x2 voxels (x,y,z); halo = tile + 2 each side
#define HX 12
#define HY 8
#define HZ 6
#define HROW 12
#define HPLN 96
#define HSP  576
#define CPAD 16          // dense 32B/voxel slot (2-way bank aliasing = free)
#define OSTR 72          // s_off row stride in f16 (36 dwords: rows != 0 mod 32 banks)

#define WSW_CH (14*6*64)       // Wsw: 5376 chunks x 8 f16 = 86016 B
#define KSW_CH (14*64)         // Ksw: 896 chunks x 8 f16 (tap-pair A-frags) = 14336 B
#define KSW_OFF 86016

__device__ inline half2v h2of(half8 v, int d) {
    half2v r; r.x = v[2*d]; r.y = v[2*d+1]; return r;
}

// ---------------- prep: pk -> Wsw (phase-1 A-frags), kern -> Ksw (phase-2 pair A-frags) ----
// Wsw chunk t=(s*6+mt)*64+lane: m=16mt+(lane&15); k=32s+8*(lane>>4)+j; W[m][k]=pk[kt][c][m], k=kt*16+c
// Ksw chunk u=s*64+lane (16x16x32 A): o=lane&15, k=(lane>>4)*8+j; kt=2s+(k>>4), c=k&15; A=kern[kt][c][o]
__global__ __launch_bounds__(256) void prep_weights(const float* __restrict__ pk,
                                                    const float* __restrict__ kern,
                                                    _Float16* __restrict__ Wsw,
                                                    _Float16* __restrict__ Ksw) {
    int t = blockIdx.x * 256 + threadIdx.x;
    if (t < WSW_CH) {
        int lane = t & 63;
        int sm = t >> 6;
        int s = sm / 6, mt = sm - 6 * s;
        int m = mt * 16 + (lane & 15);
        int q = lane >> 4;
        half8 w;
#pragma unroll
        for (int j = 0; j < 8; ++j) {
            int k = 32 * s + 8 * q + j;
            int kt = k >> 4, c = k & 15;
            float wv = (kt < K && m < 81) ? pk[kt * 1296 + c * 81 + m] : 0.0f;
            w[j] = (_Float16)wv;
        }
        *(half8*)(Wsw + t * 8) = w;
    } else if (t < WSW_CH + KSW_CH) {
        int u = t - WSW_CH;
        int s = u >> 6, lane = u & 63;
        int o = lane & 15, q = lane >> 4;
        half8 w;
#pragma unroll
        for (int j = 0; j < 8; ++j) {
            int k = q * 8 + j;
            int kt = 2 * s + (k >> 4), c = k & 15;
            float wv = (kt < K) ? kern[kt * 256 + c * 16 + o] : 0.0f;
            w[j] = (_Float16)wv;
        }
        *(half8*)(Ksw + u * 8) = w;
    }
}

// ---------------- main fused kernel ----------------
__global__ __launch_bounds__(256, 5) void deform_main(
    const float* __restrict__ x,          // [16][64][64][64] fp32
    const _Float16* __restrict__ Wsw,     // phase-1 A-frags
    const _Float16* __restrict__ Ksw,     // phase-2 tap-pair A-frags
    float* __restrict__ out)              // [16][64][64][64]
{
    __shared__ _Float16 s_h[HSP * CPAD];    // 18432 B halo
    __shared__ _Float16 s_off[81 * OSTR];   // 11664 B offsets f16
    // total 30096 B -> 5 blocks/CU

    const int tid  = threadIdx.x;
    const int lane = tid & 63;
    const int wave = __builtin_amdgcn_readfirstlane(tid >> 6);

    const int bx0 = blockIdx.x * 8;
    const int by0 = blockIdx.y * 4;
    const int bz0 = blockIdx.z * 2;

    // ---- Phase 0: stage halo, fp32 -> channel-last f16 inline ----
    for (int i = tid; i < HSP; i += 256) {
        int z = i / HPLN;
        int r = i - z * HPLN;
        int y = r / HROW;
        int xx = r - y * HROW;
        int gz = bz0 - 2 + z, gy = by0 - 2 + y, gx = bx0 - 2 + xx;
        bool in = (unsigned)gz < D && (unsigned)gy < D && (unsigned)gx < D;
        half8 a = {}, b = {};
        if (in) {
            const float* p = x + (gz * DD + gy * D + gx);
#pragma unroll
            for (int c = 0; c < 8; ++c) a[c] = (_Float16)p[c * DDD];
#pragma unroll
            for (int c = 0; c < 8; ++c) b[c] = (_Float16)p[(c + 8) * DDD];
        }
        *(half8*)(s_h + i * CPAD)     = a;
        *(half8*)(s_h + i * CPAD + 8) = b;
    }
    __syncthreads();

    // voxel mapping shared by phases 1 & 2: v = wave*16 + n, n = lane&15
    // (tz,ty,tx) = (wave>>1, 2*(wave&1)+(n>>3), n&7)
    const int n = lane & 15, q = lane >> 4;
    const int tz = wave >> 1;
    const int ty = 2 * (wave & 1) + (n >> 3);
    const int tx = n & 7;
    const int v = wave * 16 + n;

    // ---- Phase 1: offset conv as f16 MFMA implicit GEMM (M=96,K=448,N=64) ----
    {
        f32x4 acc[6] = {};
        for (int s = 0; s < 14; ++s) {
            int kt = 2 * s + (q >> 1);
            int ktc = (kt < K) ? kt : 0;              // pad taps: W rows are zero
            int kd = ktc / 9, kh = (ktc / 3) % 3, kw = ktc % 3;
            int idx = (tz + kd + 1) * HPLN + (ty + kh + 1) * HROW + (tx + kw + 1);
            half8 bfrag = *(const half8*)(s_h + idx * CPAD + (q & 1) * 8);
#pragma unroll
            for (int mt = 0; mt < 6; ++mt) {
                half8 afrag = *(const half8*)(Wsw + ((s * 6 + mt) * 64 + lane) * 8);
                acc[mt] = __builtin_amdgcn_mfma_f32_16x16x32_f16(afrag, bfrag, acc[mt], 0, 0, 0);
            }
        }
#pragma unroll
        for (int mt = 0; mt < 6; ++mt)
#pragma unroll
            for (int r = 0; r < 4; ++r) {
                int o = mt * 16 + q * 4 + r;
                if (o < 81) s_off[o * OSTR + v] = (_Float16)acc[mt][r];
            }
    }
    __syncthreads();

    // ---- Phase 2: tap-pair gather + 16x16x32 MFMA; wave covers ALL taps for its 16 voxels ----
    // lane (n,q): voxel n, tap kt = 2s + (q>>1), channels (q&1)*8..+7  == B-frag layout
    const int gz = bz0 + tz, gy = by0 + ty, gx = bx0 + tx;
    const int cbase = (q & 1) * 8;

    f32x4 acc2 = {};                      // C[o = 4q+r][16 voxels]

    for (int s = 0; s < 14; ++s) {
        const int ktr = 2 * s + (q >> 1);
        const int kt = (ktr < K) ? ktr : K - 1;       // clamp: A rows for tap 27 are zero
        const int kd = kt / 9, kh = (kt / 3) % 3, kw = kt % 3;
        float cz = (float)(gz + kd - 1) + (float)s_off[(3 * kt + 0) * OSTR + v];
        float cy = (float)(gy + kh - 1) + (float)s_off[(3 * kt + 1) * OSTR + v];
        float cx = (float)(gx + kw - 1) + (float)s_off[(3 * kt + 2) * OSTR + v];
        float zf = floorf(cz), yf = floorf(cy), xf = floorf(cx);
        float fz = cz - zf, fy = cy - yf, fx = cx - xf;
        int z0 = (int)zf, y0 = (int)yf, x0 = (int)xf;
        int hz0 = z0 - bz0 + 2, hy0 = y0 - by0 + 2, hx0 = x0 - bx0 + 2;

        half2v val2[4] = {};              // this lane's 8 channels (4 x half2)
        if ((unsigned)hz0 < (unsigned)(HZ - 1) && (unsigned)hy0 < (unsigned)(HY - 1)
            && (unsigned)hx0 < (unsigned)(HX - 1)) {
#pragma unroll
            for (int dz = 0; dz < 2; ++dz) {
                float wz = dz ? fz : 1.0f - fz;
#pragma unroll
                for (int dy = 0; dy < 2; ++dy) {
                    float wzy = wz * (dy ? fy : 1.0f - fy);
#pragma unroll
                    for (int dx = 0; dx < 2; ++dx) {
                        float w = wzy * (dx ? fx : 1.0f - fx);
                        int idx = (hz0 + dz) * HPLN + (hy0 + dy) * HROW + (hx0 + dx);
                        half8 cc = *(const half8*)(s_h + idx * CPAD + cbase);
                        _Float16 wh = (_Float16)w;
                        half2v w2; w2.x = wh; w2.y = wh;
#pragma unroll
                        for (int d = 0; d < 4; ++d)
                            val2[d] += w2 * h2of(cc, d);
                    }
                }
            }
        } else {
            // rare: |offset| >= 1 pushed a corner outside the halo
            f32x2 valf[4] = {};
#pragma unroll
            for (int dz = 0; dz < 2; ++dz) {
                int zi = z0 + dz;
                float wz = dz ? fz : 1.0f - fz;
#pragma unroll
                for (int dy = 0; dy < 2; ++dy) {
                    int yi = y0 + dy;
                    float wzy = wz * (dy ? fy : 1.0f - fy);
#pragma unroll
                    for (int dx = 0; dx < 2; ++dx) {
                        int xi = x0 + dx;
                        if ((unsigned)zi < D && (unsigned)yi < D && (unsigned)xi < D) {
                            float w = wzy * (dx ? fx : 1.0f - fx);
                            int base = zi * DD + yi * D + xi;
#pragma unroll
                            for (int d = 0; d < 4; ++d) {
                                valf[d].x += w * x[(cbase + 2 * d)     * DDD + base];
                                valf[d].y += w * x[(cbase + 2 * d + 1) * DDD + base];
                            }
                        }
                    }
                }
            }
#pragma unroll
            for (int d = 0; d < 4; ++d) {
                val2[d].x = (_Float16)valf[d].x;
                val2[d].y = (_Float16)valf[d].y;
            }
        }

        // registers already ARE the B-fragment: B[k = 8q+j][n]
        half8 bf;
#pragma unroll
        for (int d = 0; d < 4; ++d) { bf[2*d] = val2[d].x; bf[2*d+1] = val2[d].y; }
        half8 af = *(const half8*)(Ksw + (s * 64 + lane) * 8);
        acc2 = __builtin_amdgcn_mfma_f32_16x16x32_f16(af, bf, acc2, 0, 0, 0);
    }

    // ---- epilogue: each wave owns complete outputs for its 16 voxels ----
    // C layout: col = n (voxel), row = q*4 + r = o
    const int opos = gz * DD + gy * D + gx;
#pragma unroll
    for (int r = 0; r < 4; ++r) {
        int o = q * 4 + r;
        out[o * DDD + opos] = acc2[r];
    }
}

extern "C" void kernel_launch(void* const* d_in, const int* in_sizes, int n_in,
                              void* d_out, int out_size, void* d_ws, size_t ws_size,
                              hipStream_t stream) {
    const float* x    = (const float*)d_in[0];
    const float* kern = (const float*)d_in[1];
    const float* pk   = (const float*)d_in[2];
    float* out = (float*)d_out;

    _Float16* Wsw = (_Float16*)d_ws;
    _Float16* Ksw = (_Float16*)((char*)d_ws + KSW_OFF);

    prep_weights<<<25, 256, 0, stream>>>(pk, kern, Wsw, Ksw);
    deform_main<<<dim3(8, 16, 32), 256, 0, stream>>>(x, Wsw, Ksw, out);
}

// Round 10
// 150.312 us; speedup vs baseline: 1.1728x; 1.0346x over previous
//
#include <hip/hip_runtime.h>

#define D 64
#define DD 4096
#define DDD 262144
#define K 27

typedef _Float16 half8  __attribute__((ext_vector_type(8)));
typedef _Float16 half2v __attribute__((ext_vector_type(2)));
typedef float    f32x4  __attribute__((ext_vector_type(4)));
typedef float    f32x2  __attribute__((ext_vector_type(2)));

__device__ inline half2v pk2(float w) {
    return __builtin_bit_cast(half2v, __builtin_amdgcn_cvt_pkrtz(w, w));
}

// tile 8x4x2 voxels (x,y,z); halo = tile + 2 each side
#define HX 12
#define HY 8
#define HZ 6
#define HROW 12
#define HPLN 96
#define HSP  576
#define CPAD 16          // dense 32B/voxel slot (2-way bank aliasing = free)
#define OSTR 72          // s_off row stride in f16 (36 dwords: rows != 0 mod 32 banks)

#define WSW_CH (14*6*64)       // Wsw: 5376 chunks x 8 f16 = 86016 B
#define KSW_CH (14*64)         // Ksw: 896 chunks x 8 f16 (tap-pair A-frags) = 14336 B
#define KSW_OFF 86016

__device__ inline half2v h2of(half8 v, int d) {
    half2v r; r.x = v[2*d]; r.y = v[2*d+1]; return r;
}

// ---------------- prep: pk -> Wsw (phase-1 A-frags), kern -> Ksw (phase-2 pair A-frags) ----
// Wsw chunk t=(s*6+mt)*64+lane: m=16mt+(lane&15); k=32s+8*(lane>>4)+j; W[m][k]=pk[kt][c][m], k=kt*16+c
// Ksw chunk u=s*64+lane (16x16x32 A): o=lane&15, k=(lane>>4)*8+j; kt=2s+(k>>4), c=k&15; A=kern[kt][c][o]
__global__ __launch_bounds__(256) void prep_weights(const float* __restrict__ pk,
                                                    const float* __restrict__ kern,
                                                    _Float16* __restrict__ Wsw,
                                                    _Float16* __restrict__ Ksw) {
    int t = blockIdx.x * 256 + threadIdx.x;
    if (t < WSW_CH) {
        int lane = t & 63;
        int sm = t >> 6;
        int s = sm / 6, mt = sm - 6 * s;
        int m = mt * 16 + (lane & 15);
        int q = lane >> 4;
        half8 w;
#pragma unroll
        for (int j = 0; j < 8; ++j) {
            int k = 32 * s + 8 * q + j;
            int kt = k >> 4, c = k & 15;
            float wv = (kt < K && m < 81) ? pk[kt * 1296 + c * 81 + m] : 0.0f;
            w[j] = (_Float16)wv;
        }
        *(half8*)(Wsw + t * 8) = w;
    } else if (t < WSW_CH + KSW_CH) {
        int u = t - WSW_CH;
        int s = u >> 6, lane = u & 63;
        int o = lane & 15, q = lane >> 4;
        half8 w;
#pragma unroll
        for (int j = 0; j < 8; ++j) {
            int k = q * 8 + j;
            int kt = 2 * s + (k >> 4), c = k & 15;
            float wv = (kt < K) ? kern[kt * 256 + c * 16 + o] : 0.0f;
            w[j] = (_Float16)wv;
        }
        *(half8*)(Ksw + u * 8) = w;
    }
}

// ---------------- main fused kernel ----------------
__global__ __launch_bounds__(256, 5) void deform_main(
    const float* __restrict__ x,          // [16][64][64][64] fp32
    const _Float16* __restrict__ Wsw,     // phase-1 A-frags
    const _Float16* __restrict__ Ksw,     // phase-2 tap-pair A-frags
    float* __restrict__ out)              // [16][64][64][64]
{
    __shared__ _Float16 s_h[HSP * CPAD];    // 18432 B halo
    __shared__ _Float16 s_off[81 * OSTR];   // 11664 B offsets f16
    // total 30096 B -> 5 blocks/CU

    const int tid  = threadIdx.x;
    const int lane = tid & 63;
    const int wave = __builtin_amdgcn_readfirstlane(tid >> 6);

    const int bx0 = blockIdx.x * 8;
    const int by0 = blockIdx.y * 4;
    const int bz0 = blockIdx.z * 2;

    // ---- Phase 0: stage halo, fp32 -> channel-last f16 inline ----
    for (int i = tid; i < HSP; i += 256) {
        int z = i / HPLN;
        int r = i - z * HPLN;
        int y = r / HROW;
        int xx = r - y * HROW;
        int gz = bz0 - 2 + z, gy = by0 - 2 + y, gx = bx0 - 2 + xx;
        bool in = (unsigned)gz < D && (unsigned)gy < D && (unsigned)gx < D;
        half8 a = {}, b = {};
        if (in) {
            const float* p = x + (gz * DD + gy * D + gx);
#pragma unroll
            for (int c = 0; c < 8; ++c) a[c] = (_Float16)p[c * DDD];
#pragma unroll
            for (int c = 0; c < 8; ++c) b[c] = (_Float16)p[(c + 8) * DDD];
        }
        *(half8*)(s_h + i * CPAD)     = a;
        *(half8*)(s_h + i * CPAD + 8) = b;
    }
    __syncthreads();

    // voxel mapping shared by phases 1 & 2: v = wave*16 + n, n = lane&15
    // (tz,ty,tx) = (wave>>1, 2*(wave&1)+(n>>3), n&7)
    const int n = lane & 15, q = lane >> 4;
    const int tz = wave >> 1;
    const int ty = 2 * (wave & 1) + (n >> 3);
    const int tx = n & 7;
    const int v = wave * 16 + n;

    // ---- Phase 1: offset conv as f16 MFMA implicit GEMM (M=96,K=448,N=64) ----
    {
        f32x4 acc[6] = {};
        for (int s = 0; s < 14; ++s) {
            int kt = 2 * s + (q >> 1);
            int ktc = (kt < K) ? kt : 0;              // pad taps: W rows are zero
            int kd = ktc / 9, kh = (ktc / 3) % 3, kw = ktc % 3;
            int idx = (tz + kd + 1) * HPLN + (ty + kh + 1) * HROW + (tx + kw + 1);
            half8 bfrag = *(const half8*)(s_h + idx * CPAD + (q & 1) * 8);
#pragma unroll
            for (int mt = 0; mt < 6; ++mt) {
                half8 afrag = *(const half8*)(Wsw + ((s * 6 + mt) * 64 + lane) * 8);
                acc[mt] = __builtin_amdgcn_mfma_f32_16x16x32_f16(afrag, bfrag, acc[mt], 0, 0, 0);
            }
        }
#pragma unroll
        for (int mt = 0; mt < 6; ++mt)
#pragma unroll
            for (int r = 0; r < 4; ++r) {
                int o = mt * 16 + q * 4 + r;
                if (o < 81) s_off[o * OSTR + v] = (_Float16)acc[mt][r];
            }
    }
    __syncthreads();

    // ---- Phase 2: tap-pair gather + 16x16x32 MFMA; wave covers ALL taps for its 16 voxels ----
    // lane (n,q): voxel n, tap kt = 2s + (q>>1), channels (q&1)*8..+7  == B-frag layout
    const int gz = bz0 + tz, gy = by0 + ty, gx = bx0 + tx;
    const int cbase = (q & 1) * 8;
    const int qh = q >> 1;

    f32x4 acc2 = {};                      // C[o = 4q+r][16 voxels]

#pragma unroll
    for (int s = 0; s < 14; ++s) {
        const int ktr = 2 * s + qh;                   // s const after unroll: 2-way cndmask
        const int kt = (ktr < K) ? ktr : K - 1;       // clamp: A rows for tap 27 are zero
        const int kd = kt / 9, kh = (kt / 3) % 3, kw = kt % 3;

        // one LDS base, 3 imm-offset reads
        const _Float16* offp = s_off + (3 * kt) * OSTR + v;
        float cz = (float)(gz + kd - 1) + (float)offp[0];
        float cy = (float)(gy + kh - 1) + (float)offp[OSTR];
        float cx = (float)(gx + kw - 1) + (float)offp[2 * OSTR];
        float zf = floorf(cz), yf = floorf(cy), xf = floorf(cx);
        float fz = cz - zf, fy = cy - yf, fx = cx - xf;
        int z0 = (int)zf, y0 = (int)yf, x0 = (int)xf;
        int hz0 = z0 - bz0 + 2, hy0 = y0 - by0 + 2, hx0 = x0 - bx0 + 2;

        half2v val2[4] = {};              // this lane's 8 channels (4 x half2)
        if ((unsigned)hz0 < (unsigned)(HZ - 1) && (unsigned)hy0 < (unsigned)(HY - 1)
            && (unsigned)hx0 < (unsigned)(HX - 1)) {
            // one base pointer; 8 corners at compile-time byte offsets
            const _Float16* cp = s_h + (hz0 * HPLN + hy0 * HROW + hx0) * CPAD + cbase;
            float gz1 = 1.0f - fz, gy1 = 1.0f - fy, gx1 = 1.0f - fx;
            float wyx00 = gy1 * gx1, wyx01 = gy1 * fx;
            float wyx10 = fy * gx1,  wyx11 = fy * fx;
#pragma unroll
            for (int dz = 0; dz < 2; ++dz) {
                float wz = dz ? fz : gz1;
                const _Float16* cpz = cp + dz * (HPLN * CPAD);
                half2v h00 = pk2(wz * wyx00);
                half2v h01 = pk2(wz * wyx01);
                half2v h10 = pk2(wz * wyx10);
                half2v h11 = pk2(wz * wyx11);
                half8 c00 = *(const half8*)(cpz);
                half8 c01 = *(const half8*)(cpz + CPAD);
                half8 c10 = *(const half8*)(cpz + HROW * CPAD);
                half8 c11 = *(const half8*)(cpz + (HROW + 1) * CPAD);
#pragma unroll
                for (int d = 0; d < 4; ++d) {
                    val2[d] += h00 * h2of(c00, d);
                    val2[d] += h01 * h2of(c01, d);
                    val2[d] += h10 * h2of(c10, d);
                    val2[d] += h11 * h2of(c11, d);
                }
            }
        } else {
            // rare: |offset| >= 1 pushed a corner outside the halo
            f32x2 valf[4] = {};
#pragma unroll
            for (int dz = 0; dz < 2; ++dz) {
                int zi = z0 + dz;
                float wz = dz ? fz : 1.0f - fz;
#pragma unroll
                for (int dy = 0; dy < 2; ++dy) {
                    int yi = y0 + dy;
                    float wzy = wz * (dy ? fy : 1.0f - fy);
#pragma unroll
                    for (int dx = 0; dx < 2; ++dx) {
                        int xi = x0 + dx;
                        if ((unsigned)zi < D && (unsigned)yi < D && (unsigned)xi < D) {
                            float w = wzy * (dx ? fx : 1.0f - fx);
                            int base = zi * DD + yi * D + xi;
#pragma unroll
                            for (int d = 0; d < 4; ++d) {
                                valf[d].x += w * x[(cbase + 2 * d)     * DDD + base];
                                valf[d].y += w * x[(cbase + 2 * d + 1) * DDD + base];
                            }
                        }
                    }
                }
            }
#pragma unroll
            for (int d = 0; d < 4; ++d) {
                val2[d].x = (_Float16)valf[d].x;
                val2[d].y = (_Float16)valf[d].y;
            }
        }

        // registers already ARE the B-fragment: B[k = 8q+j][n]
        half8 bf;
#pragma unroll
        for (int d = 0; d < 4; ++d) { bf[2*d] = val2[d].x; bf[2*d+1] = val2[d].y; }
        half8 af = *(const half8*)(Ksw + (s * 64 + lane) * 8);
        acc2 = __builtin_amdgcn_mfma_f32_16x16x32_f16(af, bf, acc2, 0, 0, 0);
    }

    // ---- epilogue: each wave owns complete outputs for its 16 voxels ----
    // C layout: col = n (voxel), row = q*4 + r = o
    const int opos = gz * DD + gy * D + gx;
#pragma unroll
    for (int r = 0; r < 4; ++r) {
        int o = q * 4 + r;
        out[o * DDD + opos] = acc2[r];
    }
}

extern "C" void kernel_launch(void* const* d_in, const int* in_sizes, int n_in,
                              void* d_out, int out_size, void* d_ws, size_t ws_size,
                              hipStream_t stream) {
    const float* x    = (const float*)d_in[0];
    const float* kern = (const float*)d_in[1];
    const float* pk   = (const float*)d_in[2];
    float* out = (float*)d_out;

    _Float16* Wsw = (_Float16*)d_ws;
    _Float16* Ksw = (_Float16*)((char*)d_ws + KSW_OFF);

    prep_weights<<<25, 256, 0, stream>>>(pk, kern, Wsw, Ksw);
    deform_main<<<dim3(8, 16, 32), 256, 0, stream>>>(x, Wsw, Ksw, out);
}